// Round 2
// baseline (197.384 us; speedup 1.0000x reference)
//
#include <hip/hip_runtime.h>
#include <math.h>

// Problem constants (B, C, H, W) = (32, 10, 192, 320), fp32.
constexpr int B_ = 32, C_ = 10, H_ = 192, W_ = 320;
constexpr int HW_  = H_ * W_;        // 61440 (divisible by 4)
constexpr int CHW_ = C_ * HW_;       // 614400
constexpr int NPTS = B_ * HW_;       // 1966080 spatial points
constexpr int NV4  = NPTS / 4;       // 491520 float4 points
constexpr int NBLK = NV4 / 256;      // 1920 blocks, exact cover

// Partial-sum slots, one row per accumulator, one column per block:
// ws[slot * NBLK + blk]. Every block writes all 11 slots unconditionally,
// so no memset of ws is needed (harness poisons it with 0xAA).
// 0: nv            (sum mvf)
// 1: num_pos
// 2: sum pos*(g0-r0)^2*log(safe+EPS)           (pos_term = -this)
// 3: sum neg*r0^2*log(1+EPS-safe)*(1-g0)^4     (neg_term = -this)
// 4: s_pos   sl1(r1-g1)+sl1(r2-g2)             masked
// 5: s_len1  sl1(r3-g3)+sl1(r6-g6)             masked
// 6: s_len2  sl1(r3-g6)+sl1(r6-g3)             masked
// 7: s_trig1 (r4-g4)^2+(r7-g7)^2+(r5-g5)^2+(r8-g8)^2  masked
// 8: s_trig2 (r4-g7)^2+(r7-g4)^2+(r5-g8)^2+(r8-g5)^2  masked
// 9: s_const (1-r5^2-r4^2)^2+(1-r8^2-r7^2)^2   masked
// 10: s_h    sl1(r9-g9)                        masked
#define NACC 11

__device__ __forceinline__ float sl1f(float d) {
    float ad = fabsf(d);
    return ad < 1.0f ? 0.5f * d * d : ad - 0.5f;
}

// __launch_bounds__(256, 4): 4 blocks/CU min -> VGPR cap ~128, enough to keep
// all 18 sparse float4 loads in flight (one memory epoch, not five).
__global__ __launch_bounds__(256, 4) void loss_main(
    const float* __restrict__ re, const float* __restrict__ gt,
    float* __restrict__ ws)
{
    const int tid = blockIdx.x * 256 + threadIdx.x;
    float acc[NACC];
#pragma unroll
    for (int i = 0; i < NACC; ++i) acc[i] = 0.0f;

    {
        const int p = tid * 4;
        const int b = p / HW_;
        const int s = p - b * HW_;
        const float* rp = re + (size_t)b * CHW_ + s;
        const float* gp = gt + (size_t)b * CHW_ + s;

        const float4 g4 = *(const float4*)gp;
        const float4 r4 = *(const float4*)rp;
        float gv[4] = {g4.x, g4.y, g4.z, g4.w};
        float rv[4] = {r4.x, r4.y, r4.z, r4.w};
        float mv[4];
        float any = 0.0f;

#pragma unroll
        for (int j = 0; j < 4; ++j) {
            const float g = gv[j], r = rv[j];
            const float m = (g == 1.0f) ? 1.0f : 0.0f;
            mv[j] = m; any += m;
            acc[0] += m;
            const float pos = (g >= 0.1f) ? 1.0f : 0.0f;
            const float neg = ((g >= 0.0f) && (g < 0.1f)) ? 1.0f : 0.0f;
            acc[1] += pos;
            const float safe = fminf(fmaxf(r, 1e-6f), 1.0f - 1e-6f);
            const float d = g - r;
            acc[2] += pos * (d * d) * logf(safe + 6e-8f);
            const float omg = 1.0f - g;
            const float omg2 = omg * omg;
            acc[3] += neg * (r * r) * logf(1.0f + 6e-8f - safe) * (omg2 * omg2);
        }

        // channels 1..9 only matter where gt0 == 1.0 (~5% of points);
        // exec-masked loads skip untouched 64B sectors.
        if (any != 0.0f) {
            float rc[9][4], gc[9][4];
#pragma unroll
            for (int c = 0; c < 9; ++c) {
                const float4 t = *(const float4*)(rp + (c + 1) * HW_);
                rc[c][0] = t.x; rc[c][1] = t.y; rc[c][2] = t.z; rc[c][3] = t.w;
                const float4 u = *(const float4*)(gp + (c + 1) * HW_);
                gc[c][0] = u.x; gc[c][1] = u.y; gc[c][2] = u.z; gc[c][3] = u.w;
            }
#pragma unroll
            for (int j = 0; j < 4; ++j) {
                const float m = mv[j];
                const float r1 = rc[0][j], r2 = rc[1][j], r3 = rc[2][j];
                const float r4v = rc[3][j], r5 = rc[4][j], r6 = rc[5][j];
                const float r7 = rc[6][j], r8 = rc[7][j], r9 = rc[8][j];
                const float g1 = gc[0][j], g2 = gc[1][j], g3 = gc[2][j];
                const float g4v = gc[3][j], g5 = gc[4][j], g6 = gc[5][j];
                const float g7 = gc[6][j], g8 = gc[7][j], g9 = gc[8][j];

                acc[4] += m * (sl1f(r1 - g1) + sl1f(r2 - g2));
                acc[5] += m * (sl1f(r3 - g3) + sl1f(r6 - g6));
                acc[6] += m * (sl1f(r3 - g6) + sl1f(r6 - g3));
                const float d44 = r4v - g4v, d77 = r7 - g7;
                const float d55 = r5 - g5,  d88 = r8 - g8;
                acc[7] += m * (d44 * d44 + d77 * d77 + d55 * d55 + d88 * d88);
                const float d47 = r4v - g7, d74 = r7 - g4v;
                const float d58 = r5 - g8,  d85 = r8 - g5;
                acc[8] += m * (d47 * d47 + d74 * d74 + d58 * d58 + d85 * d85);
                const float c1 = 1.0f - r5 * r5 - r4v * r4v;
                const float c2 = 1.0f - r8 * r8 - r7 * r7;
                acc[9] += m * (c1 * c1 + c2 * c2);
                acc[10] += m * sl1f(r9 - g9);
            }
        }
    }

    // block reduction: wave shuffle (64 lanes) -> LDS (4 waves) -> plain store
    __shared__ float smem[NACC][4];
    const int lane = threadIdx.x & 63;
    const int wid  = threadIdx.x >> 6;
#pragma unroll
    for (int i = 0; i < NACC; ++i) {
        float v = acc[i];
#pragma unroll
        for (int off = 32; off > 0; off >>= 1) v += __shfl_down(v, off, 64);
        if (lane == 0) smem[i][wid] = v;
    }
    __syncthreads();
    if (threadIdx.x < NACC) {
        const int i = threadIdx.x;
        ws[i * NBLK + blockIdx.x] =
            smem[i][0] + smem[i][1] + smem[i][2] + smem[i][3];
    }
}

// One block: reduce 1920 partials per slot, then apply the loss formula.
__global__ __launch_bounds__(256) void loss_reduce(
    const float* __restrict__ ws, float* __restrict__ out)
{
    __shared__ float slot_sum[NACC];
    __shared__ float smem[4];
    const int lane = threadIdx.x & 63;
    const int wid  = threadIdx.x >> 6;

    for (int i = 0; i < NACC; ++i) {
        float v = 0.0f;
        for (int b = threadIdx.x; b < NBLK; b += 256)
            v += ws[i * NBLK + b];
#pragma unroll
        for (int off = 32; off > 0; off >>= 1) v += __shfl_down(v, off, 64);
        if (lane == 0) smem[wid] = v;
        __syncthreads();
        if (threadIdx.x == 0)
            slot_sum[i] = smem[0] + smem[1] + smem[2] + smem[3];
        __syncthreads();
    }

    if (threadIdx.x == 0) {
        const float nv     = slot_sum[0];
        const float npos   = slot_sum[1];
        const float pterm  = -slot_sum[2];
        const float nterm  = -slot_sum[3];
        const float focal  = (npos == 0.0f) ? nterm : (pterm + nterm) / npos;

        const float inv2nv = 1.0f / (2.0f * nv);
        const float invnv  = 1.0f / nv;

        const float pos_loss = 1.0f * slot_sum[4] * inv2nv;   // POS_W
        const float lv1      = 0.1f * slot_sum[5] * inv2nv;   // LEN_W
        const float lv2      = 0.1f * slot_sum[6] * inv2nv;
        const float tv1      = 1.0f * slot_sum[7] * inv2nv;   // TRIG_W
        const float tv2      = 1.0f * slot_sum[8] * inv2nv;
        const float cl       = 0.5f * slot_sum[9] * invnv;    // CONST_W
        const float hl       = 0.1f * slot_sum[10] * invnv;   // LEN_W

        const float dims = fminf(lv1 + tv1, lv2 + tv2) + hl;
        out[0] = 1.0f * focal + pos_loss + dims + cl;         // CONF_W
    }
}

extern "C" void kernel_launch(void* const* d_in, const int* in_sizes, int n_in,
                              void* d_out, int out_size, void* d_ws, size_t ws_size,
                              hipStream_t stream)
{
    const float* re = (const float*)d_in[0];
    const float* gt = (const float*)d_in[1];
    float* ws  = (float*)d_ws;
    float* out = (float*)d_out;

    loss_main<<<NBLK, 256, 0, stream>>>(re, gt, ws);
    loss_reduce<<<1, 256, 0, stream>>>(ws, out);
}

// Round 3
// 197.300 us; speedup vs baseline: 1.0004x; 1.0004x over previous
//
#include <hip/hip_runtime.h>
#include <math.h>

// Problem constants (B, C, H, W) = (32, 10, 192, 320), fp32.
constexpr int B_ = 32, C_ = 10, H_ = 192, W_ = 320;
constexpr int HW_  = H_ * W_;        // 61440 (divisible by 4)
constexpr int CHW_ = C_ * HW_;       // 614400
constexpr int NPTS = B_ * HW_;       // 1966080 spatial points
constexpr int NV4  = NPTS / 4;       // 491520 float4 points
constexpr int NBLK = NV4 / 256;      // 1920 blocks, exact cover

// Partial-sum slots: ws[slot * NBLK + blk]; every block writes all slots
// unconditionally (harness poisons ws with 0xAA, no memset needed).
// 0: nv  1: num_pos  2: pos-focal-sum  3: neg-focal-sum
// 4: s_pos  5: s_len1  6: s_len2  7: s_trig1  8: s_trig2  9: s_const  10: s_h
#define NACC 11

__device__ __forceinline__ float sl1f(float d) {
    float ad = fabsf(d);
    return ad < 1.0f ? 0.5f * d * d : ad - 0.5f;
}

// Dense streaming version: NO divergent loads. Round-2 evidence showed the
// exec-masked sparse gather path is latency-bound at ~1.2 TB/s (55 us even
// with inputs L3-resident); dense coalesced float4 streams run at ~6 TB/s,
// so reading everything (157 MB) is ~2x faster than fetching 63.5 MB sparsely.
__global__ __launch_bounds__(256) void loss_main(
    const float* __restrict__ re, const float* __restrict__ gt,
    float* __restrict__ ws)
{
    const int tid = blockIdx.x * 256 + threadIdx.x;
    const int p = tid * 4;
    const int b = p / HW_;
    const int s = p - b * HW_;
    const float* rp = re + (size_t)b * CHW_ + s;
    const float* gp = gt + (size_t)b * CHW_ + s;

    // One load epoch: all 20 coalesced float4 streams issued back-to-back.
    float4 R[10], G[10];
#pragma unroll
    for (int c = 0; c < 10; ++c) {
        R[c] = *(const float4*)(rp + c * HW_);
        G[c] = *(const float4*)(gp + c * HW_);
    }

    float acc[NACC];
#pragma unroll
    for (int i = 0; i < NACC; ++i) acc[i] = 0.0f;

#pragma unroll
    for (int j = 0; j < 4; ++j) {
        const float* Rj = (const float*)&R[0];  // float4 arrays are contiguous
        const float* Gj = (const float*)&G[0];
        // channel c, element j of this thread's 4 points:
        #define RC(c) (((const float*)&R[c])[j])
        #define GC(c) (((const float*)&G[c])[j])
        const float g = GC(0), r = RC(0);
        const float m = (g == 1.0f) ? 1.0f : 0.0f;
        acc[0] += m;
        const float pos = (g >= 0.1f) ? 1.0f : 0.0f;
        const float neg = ((g >= 0.0f) && (g < 0.1f)) ? 1.0f : 0.0f;
        acc[1] += pos;
        const float safe = fminf(fmaxf(r, 1e-6f), 1.0f - 1e-6f);
        const float d0 = g - r;
        acc[2] += pos * (d0 * d0) * logf(safe + 6e-8f);
        const float omg = 1.0f - g;
        const float omg2 = omg * omg;
        acc[3] += neg * (r * r) * logf(1.0f + 6e-8f - safe) * (omg2 * omg2);

        const float r1 = RC(1), r2 = RC(2), r3 = RC(3), r4v = RC(4);
        const float r5 = RC(5), r6 = RC(6), r7 = RC(7), r8 = RC(8), r9 = RC(9);
        const float g1 = GC(1), g2 = GC(2), g3 = GC(3), g4v = GC(4);
        const float g5 = GC(5), g6 = GC(6), g7 = GC(7), g8 = GC(8), g9 = GC(9);

        acc[4] += m * (sl1f(r1 - g1) + sl1f(r2 - g2));
        acc[5] += m * (sl1f(r3 - g3) + sl1f(r6 - g6));
        acc[6] += m * (sl1f(r3 - g6) + sl1f(r6 - g3));
        const float d44 = r4v - g4v, d77 = r7 - g7;
        const float d55 = r5 - g5,  d88 = r8 - g8;
        acc[7] += m * (d44 * d44 + d77 * d77 + d55 * d55 + d88 * d88);
        const float d47 = r4v - g7, d74 = r7 - g4v;
        const float d58 = r5 - g8,  d85 = r8 - g5;
        acc[8] += m * (d47 * d47 + d74 * d74 + d58 * d58 + d85 * d85);
        const float c1 = 1.0f - r5 * r5 - r4v * r4v;
        const float c2 = 1.0f - r8 * r8 - r7 * r7;
        acc[9] += m * (c1 * c1 + c2 * c2);
        acc[10] += m * sl1f(r9 - g9);
        #undef RC
        #undef GC
        (void)Rj; (void)Gj;
    }

    // block reduction: wave shuffle (64 lanes) -> LDS (4 waves) -> plain store
    __shared__ float smem[NACC][4];
    const int lane = threadIdx.x & 63;
    const int wid  = threadIdx.x >> 6;
#pragma unroll
    for (int i = 0; i < NACC; ++i) {
        float v = acc[i];
#pragma unroll
        for (int off = 32; off > 0; off >>= 1) v += __shfl_down(v, off, 64);
        if (lane == 0) smem[i][wid] = v;
    }
    __syncthreads();
    if (threadIdx.x < NACC) {
        const int i = threadIdx.x;
        ws[i * NBLK + blockIdx.x] =
            smem[i][0] + smem[i][1] + smem[i][2] + smem[i][3];
    }
}

// One block: reduce 1920 partials per slot, then apply the loss formula.
__global__ __launch_bounds__(256) void loss_reduce(
    const float* __restrict__ ws, float* __restrict__ out)
{
    __shared__ float slot_sum[NACC];
    __shared__ float smem[4];
    const int lane = threadIdx.x & 63;
    const int wid  = threadIdx.x >> 6;

    for (int i = 0; i < NACC; ++i) {
        float v = 0.0f;
        for (int b = threadIdx.x; b < NBLK; b += 256)
            v += ws[i * NBLK + b];
#pragma unroll
        for (int off = 32; off > 0; off >>= 1) v += __shfl_down(v, off, 64);
        if (lane == 0) smem[wid] = v;
        __syncthreads();
        if (threadIdx.x == 0)
            slot_sum[i] = smem[0] + smem[1] + smem[2] + smem[3];
        __syncthreads();
    }

    if (threadIdx.x == 0) {
        const float nv     = slot_sum[0];
        const float npos   = slot_sum[1];
        const float pterm  = -slot_sum[2];
        const float nterm  = -slot_sum[3];
        const float focal  = (npos == 0.0f) ? nterm : (pterm + nterm) / npos;

        const float inv2nv = 1.0f / (2.0f * nv);
        const float invnv  = 1.0f / nv;

        const float pos_loss = 1.0f * slot_sum[4] * inv2nv;   // POS_W
        const float lv1      = 0.1f * slot_sum[5] * inv2nv;   // LEN_W
        const float lv2      = 0.1f * slot_sum[6] * inv2nv;
        const float tv1      = 1.0f * slot_sum[7] * inv2nv;   // TRIG_W
        const float tv2      = 1.0f * slot_sum[8] * inv2nv;
        const float cl       = 0.5f * slot_sum[9] * invnv;    // CONST_W
        const float hl       = 0.1f * slot_sum[10] * invnv;   // LEN_W

        const float dims = fminf(lv1 + tv1, lv2 + tv2) + hl;
        out[0] = 1.0f * focal + pos_loss + dims + cl;         // CONF_W
    }
}

extern "C" void kernel_launch(void* const* d_in, const int* in_sizes, int n_in,
                              void* d_out, int out_size, void* d_ws, size_t ws_size,
                              hipStream_t stream)
{
    const float* re = (const float*)d_in[0];
    const float* gt = (const float*)d_in[1];
    float* ws  = (float*)d_ws;
    float* out = (float*)d_out;

    loss_main<<<NBLK, 256, 0, stream>>>(re, gt, ws);
    loss_reduce<<<1, 256, 0, stream>>>(ws, out);
}

// Round 4
// 172.848 us; speedup vs baseline: 1.1419x; 1.1415x over previous
//
#include <hip/hip_runtime.h>
#include <math.h>

// Problem constants (B, C, H, W) = (32, 10, 192, 320), fp32.
constexpr int B_ = 32, C_ = 10, H_ = 192, W_ = 320;
constexpr int HW_  = H_ * W_;        // 61440 (divisible by 2)
constexpr int CHW_ = C_ * HW_;       // 614400
constexpr int NPTS = B_ * HW_;       // 1966080 spatial points
constexpr int PPT  = 2;              // points per thread
constexpr int NTHR = NPTS / PPT;     // 983040 threads
constexpr int NBLK = NTHR / 256;     // 3840 blocks, exact cover

// Partial-sum slots, ws[slot * NBLK + blk]. Final weights are folded into
// per-thread accumulation so only 7 slots survive:
// 0: nv      (sum of valid mask)
// 1: num_pos
// 2: sum pos*(g0-r0)^2*log(safe+EPS)            (pos_term = -this)
// 3: sum neg*r0^2*log(1+EPS-safe)*(1-g0)^4      (neg_term = -this)
// 4: P  = 0.5*s_pos + 0.5*s_const + 0.1*s_h     (-> P/nv)
// 5: V1 = 0.05*s_len1 + 0.5*s_trig1             (-> V1/nv)
// 6: V2 = 0.05*s_len2 + 0.5*s_trig2             (-> V2/nv)
// loss = focal + (P + min(V1,V2)) / nv
#define NACC 7

__device__ __forceinline__ float sl1f(float d) {
    float ad = fabsf(d);
    return ad < 1.0f ? 0.5f * d * d : ad - 0.5f;
}

// Latency-bound fix (round-3 evidence): 2 points/thread so all 20 channel
// loads are dwordx2 and fit in one load epoch (~40 data VGPRs); 3840 blocks
// so resident waves/CU is VGPR-capped (~24-32), not grid-drain-capped (~10).
__global__ __launch_bounds__(256) void loss_main(
    const float* __restrict__ re, const float* __restrict__ gt,
    float* __restrict__ ws)
{
    const int tid = blockIdx.x * 256 + threadIdx.x;
    const int p = tid * PPT;
    const int b = p / HW_;
    const int s = p - b * HW_;
    const float* rp = re + (size_t)b * CHW_ + s;
    const float* gp = gt + (size_t)b * CHW_ + s;

    // One load epoch: 20 independent coalesced dwordx2 loads.
    float2 R[10], G[10];
#pragma unroll
    for (int c = 0; c < 10; ++c) {
        R[c] = *(const float2*)(rp + c * HW_);
        G[c] = *(const float2*)(gp + c * HW_);
    }

    float acc[NACC];
#pragma unroll
    for (int i = 0; i < NACC; ++i) acc[i] = 0.0f;

#pragma unroll
    for (int j = 0; j < PPT; ++j) {
        #define RC(c) (((const float*)&R[c])[j])
        #define GC(c) (((const float*)&G[c])[j])
        const float g = GC(0), r = RC(0);
        const float m = (g == 1.0f) ? 1.0f : 0.0f;
        acc[0] += m;
        const float pos = (g >= 0.1f) ? 1.0f : 0.0f;
        const float neg = ((g >= 0.0f) && (g < 0.1f)) ? 1.0f : 0.0f;
        acc[1] += pos;
        const float safe = fminf(fmaxf(r, 1e-6f), 1.0f - 1e-6f);
        const float d0 = g - r;
        acc[2] += pos * (d0 * d0) * logf(safe + 6e-8f);
        const float omg = 1.0f - g;
        const float omg2 = omg * omg;
        acc[3] += neg * (r * r) * logf(1.0f + 6e-8f - safe) * (omg2 * omg2);

        const float r1 = RC(1), r2 = RC(2), r3 = RC(3), r4v = RC(4);
        const float r5 = RC(5), r6 = RC(6), r7 = RC(7), r8 = RC(8), r9 = RC(9);
        const float g1 = GC(1), g2 = GC(2), g3 = GC(3), g4v = GC(4);
        const float g5 = GC(5), g6 = GC(6), g7 = GC(7), g8 = GC(8), g9 = GC(9);

        // P: pos(0.5) + const(0.5) + height(0.1), all later /nv
        const float sp = sl1f(r1 - g1) + sl1f(r2 - g2);
        const float c1 = 1.0f - r5 * r5 - r4v * r4v;
        const float c2 = 1.0f - r8 * r8 - r7 * r7;
        const float sc = c1 * c1 + c2 * c2;
        const float sh = sl1f(r9 - g9);
        acc[4] += m * (0.5f * sp + 0.5f * sc + 0.1f * sh);

        // V1: 0.05*len1 + 0.5*trig1
        const float d44 = r4v - g4v, d77 = r7 - g7;
        const float d55 = r5 - g5,  d88 = r8 - g8;
        const float t1 = d44 * d44 + d77 * d77 + d55 * d55 + d88 * d88;
        const float l1 = sl1f(r3 - g3) + sl1f(r6 - g6);
        acc[5] += m * (0.05f * l1 + 0.5f * t1);

        // V2: 0.05*len2 + 0.5*trig2
        const float d47 = r4v - g7, d74 = r7 - g4v;
        const float d58 = r5 - g8,  d85 = r8 - g5;
        const float t2 = d47 * d47 + d74 * d74 + d58 * d58 + d85 * d85;
        const float l2 = sl1f(r3 - g6) + sl1f(r6 - g3);
        acc[6] += m * (0.05f * l2 + 0.5f * t2);
        #undef RC
        #undef GC
    }

    // block reduction: wave shuffle (64 lanes) -> LDS (4 waves) -> plain store
    __shared__ float smem[NACC][4];
    const int lane = threadIdx.x & 63;
    const int wid  = threadIdx.x >> 6;
#pragma unroll
    for (int i = 0; i < NACC; ++i) {
        float v = acc[i];
#pragma unroll
        for (int off = 32; off > 0; off >>= 1) v += __shfl_down(v, off, 64);
        if (lane == 0) smem[i][wid] = v;
    }
    __syncthreads();
    if (threadIdx.x < NACC) {
        const int i = threadIdx.x;
        ws[i * NBLK + blockIdx.x] =
            smem[i][0] + smem[i][1] + smem[i][2] + smem[i][3];
    }
}

// One block, 1024 threads: all 7*3840 partials in one parallel load epoch.
__global__ __launch_bounds__(1024) void loss_reduce(
    const float* __restrict__ ws, float* __restrict__ out)
{
    constexpr int K = NBLK / 1024;   // 3.75 -> loop to 4 with bounds check
    float acc[NACC];
#pragma unroll
    for (int i = 0; i < NACC; ++i) acc[i] = 0.0f;

#pragma unroll
    for (int k = 0; k < 4; ++k) {
        const int idx = threadIdx.x + k * 1024;
        if (idx < NBLK) {
#pragma unroll
            for (int i = 0; i < NACC; ++i)
                acc[i] += ws[i * NBLK + idx];
        }
    }
    (void)K;

    __shared__ float smem[NACC][16];
    const int lane = threadIdx.x & 63;
    const int wid  = threadIdx.x >> 6;
#pragma unroll
    for (int i = 0; i < NACC; ++i) {
        float v = acc[i];
#pragma unroll
        for (int off = 32; off > 0; off >>= 1) v += __shfl_down(v, off, 64);
        if (lane == 0) smem[i][wid] = v;
    }
    __syncthreads();

    if (threadIdx.x == 0) {
        float slot[NACC];
#pragma unroll
        for (int i = 0; i < NACC; ++i) {
            float v = 0.0f;
#pragma unroll
            for (int w = 0; w < 16; ++w) v += smem[i][w];
            slot[i] = v;
        }
        const float nv    = slot[0];
        const float npos  = slot[1];
        const float pterm = -slot[2];
        const float nterm = -slot[3];
        const float focal = (npos == 0.0f) ? nterm : (pterm + nterm) / npos;
        out[0] = focal + (slot[4] + fminf(slot[5], slot[6])) / nv;
    }
}

extern "C" void kernel_launch(void* const* d_in, const int* in_sizes, int n_in,
                              void* d_out, int out_size, void* d_ws, size_t ws_size,
                              hipStream_t stream)
{
    const float* re = (const float*)d_in[0];
    const float* gt = (const float*)d_in[1];
    float* ws  = (float*)d_ws;
    float* out = (float*)d_out;

    loss_main<<<NBLK, 256, 0, stream>>>(re, gt, ws);
    loss_reduce<<<1, 1024, 0, stream>>>(ws, out);
}